// Round 4
// baseline (738.144 us; speedup 1.0000x reference)
//
#include <hip/hip_runtime.h>
#include <hip/hip_fp16.h>
#include <math.h>

#define LEAKY 0.2f
#define BP 5                     // nodes per bucket = 32
#define BSZ 32

union H2 { __half2 h; int i; };
union H4 { __half2 h[2]; float2 f; };
union H8 { __half2 h[4]; float4 f; };

__device__ inline __half2 shfl_xor_h2(__half2 v, int m) {
    H2 u; u.h = v;
    u.i = __shfl_xor(u.i, m);
    return u.h;
}

// ---------------- CSR build (bucketed) ----------------

// per-block LDS histogram of dst buckets
__global__ __launch_bounds__(256) void khist(const int* __restrict__ dst,
                                             int* __restrict__ bhist,
                                             int E, int nbuk) {
    extern __shared__ int hist[];
    int t = threadIdx.x;
    for (int i = t; i < nbuk; i += 256) hist[i] = 0;
    __syncthreads();
    for (int e = blockIdx.x * 256 + t; e < E; e += gridDim.x * 256)
        atomicAdd(&hist[dst[e] >> BP], 1);
    __syncthreads();
    for (int i = t; i < nbuk; i += 256) {
        int v = hist[i];
        if (v) atomicAdd(&bhist[i], v);
    }
}

// single-block exclusive scan of bucket counts -> bbase, bcur
__global__ __launch_bounds__(1024) void bscan(const int* __restrict__ bhist,
                                              int* __restrict__ bbase,
                                              int* __restrict__ bcur, int nbuk) {
    __shared__ int s[1024];
    int t = threadIdx.x;
    int v[4]; int sum = 0;
    #pragma unroll
    for (int i = 0; i < 4; ++i) {
        int idx = t * 4 + i;
        v[i] = (idx < nbuk) ? bhist[idx] : 0;
        sum += v[i];
    }
    s[t] = sum; __syncthreads();
    for (int off = 1; off < 1024; off <<= 1) {
        int a = (t >= off) ? s[t - off] : 0;
        __syncthreads();
        s[t] += a;
        __syncthreads();
    }
    int run = (t > 0) ? s[t - 1] : 0;
    #pragma unroll
    for (int i = 0; i < 4; ++i) {
        int idx = t * 4 + i;
        if (idx < nbuk) { bbase[idx] = run; bcur[idx] = run; run += v[i]; }
    }
    if (t == 1023) bbase[nbuk] = s[1023];
}

// append packed (dlocal<<17)|src to bucket region
__global__ __launch_bounds__(256) void kscatter(const int* __restrict__ src,
                                                const int* __restrict__ dst,
                                                int* __restrict__ bcur,
                                                int* __restrict__ ebuf, int E) {
    int e = blockIdx.x * 256 + threadIdx.x;
    if (e >= E) return;
    int d = dst[e];
    int pos = atomicAdd(&bcur[d >> BP], 1);
    ebuf[pos] = ((d & (BSZ - 1)) << 17) | src[e];
}

// per-bucket node counts (+self-loop) and dis
__global__ __launch_bounds__(256) void kcount(const int* __restrict__ ebuf,
                                              const int* __restrict__ bbase,
                                              int* __restrict__ cnt,
                                              float* __restrict__ dis, int N) {
    __shared__ int h[BSZ];
    int b = blockIdx.x, t = threadIdx.x;
    if (t < BSZ) h[t] = 0;
    __syncthreads();
    int beg = bbase[b], end = bbase[b + 1];
    for (int j = beg + t; j < end; j += 256)
        atomicAdd(&h[(ebuf[j] >> 17) & (BSZ - 1)], 1);
    __syncthreads();
    if (t < BSZ) {
        int node = b * BSZ + t;
        if (node < N) {
            int c = h[t] + 1;
            cnt[node] = c;
            dis[node] = rsqrtf((float)c);
        }
    }
}

__global__ void scan_block(const int* __restrict__ cnt, int* rowptr, int* bsum, int n) {
    __shared__ int s[256];
    int t = threadIdx.x;
    int i = blockIdx.x * 256 + t;
    int v = (i < n) ? cnt[i] : 0;
    s[t] = v; __syncthreads();
    for (int off = 1; off < 256; off <<= 1) {
        int a = (t >= off) ? s[t - off] : 0;
        __syncthreads();
        s[t] += a;
        __syncthreads();
    }
    if (i < n) rowptr[i] = s[t] - v;
    if (t == 255) bsum[blockIdx.x] = s[255];
}

__global__ void scan_tops(int* bsum, int nb, int* rowptr, int n) {
    __shared__ int s[512];
    int t = threadIdx.x;
    int v = (t < nb) ? bsum[t] : 0;
    s[t] = v; __syncthreads();
    for (int off = 1; off < 512; off <<= 1) {
        int a = (t >= off) ? s[t - off] : 0;
        __syncthreads();
        s[t] += a;
        __syncthreads();
    }
    if (t < nb) bsum[t] = s[t] - v;
    if (t == 511) rowptr[n] = s[511];
}

__global__ void scan_add(int* rowptr, const int* __restrict__ bsum, int n) {
    int i = blockIdx.x * 256 + threadIdx.x;
    if (i < n) rowptr[i] += bsum[blockIdx.x];
}

// per-bucket placement into col (self-loop first, then bucket edges)
__global__ __launch_bounds__(256) void kplace(const int* __restrict__ ebuf,
                                              const int* __restrict__ bbase,
                                              const int* __restrict__ rowptr,
                                              int* __restrict__ col, int N) {
    __shared__ int cur[BSZ];
    int b = blockIdx.x, t = threadIdx.x;
    if (t < BSZ) {
        int node = b * BSZ + t;
        if (node < N) {
            int r = rowptr[node];
            col[r] = node;          // self-loop
            cur[t] = r + 1;
        }
    }
    __syncthreads();
    int beg = bbase[b], end = bbase[b + 1];
    for (int j = beg + t; j < end; j += 256) {
        int v = ebuf[j];
        int dl = (v >> 17) & (BSZ - 1);
        int p = atomicAdd(&cur[dl], 1);
        col[p] = v & 0x1FFFF;
    }
}

// ---------------- GEMM1: [M,256] @ [256,128] -> fp16, epilogue *= dis[row] ----------------
__global__ __launch_bounds__(256) void gemm_256_128(
        const float* __restrict__ A, const float* __restrict__ B,
        const float* __restrict__ dis, __half* __restrict__ C, int M) {
    __shared__ __align__(16) __half As[16][72];
    __shared__ __align__(16) __half Bs[16][136];
    int t = threadIdx.x;
    int bm0 = blockIdx.x * 64;
    int lm  = t >> 2;
    int lk0 = (t & 3) * 4;
    int lbk  = t >> 4;
    int lbn0 = (t & 15) * 8;
    int arow = bm0 + lm;
    bool aval = arow < M;
    const float* Arow = A + (size_t)arow * 256;
    int tm0 = (t >> 5) * 8;
    int tn0 = (t & 31) * 4;
    __half2 acc[8][2];
    #pragma unroll
    for (int i = 0; i < 8; ++i) {
        acc[i][0] = __float2half2_rn(0.f);
        acc[i][1] = __float2half2_rn(0.f);
    }
    for (int kb = 0; kb < 256; kb += 16) {
        float4 av = make_float4(0.f, 0.f, 0.f, 0.f);
        if (aval) av = *(const float4*)(Arow + kb + lk0);
        float4 bv0 = *(const float4*)(B + (size_t)(kb + lbk) * 128 + lbn0);
        float4 bv1 = *(const float4*)(B + (size_t)(kb + lbk) * 128 + lbn0 + 4);
        As[lk0 + 0][lm] = __float2half(av.x);
        As[lk0 + 1][lm] = __float2half(av.y);
        As[lk0 + 2][lm] = __float2half(av.z);
        As[lk0 + 3][lm] = __float2half(av.w);
        H8 bu;
        bu.h[0] = __floats2half2_rn(bv0.x, bv0.y);
        bu.h[1] = __floats2half2_rn(bv0.z, bv0.w);
        bu.h[2] = __floats2half2_rn(bv1.x, bv1.y);
        bu.h[3] = __floats2half2_rn(bv1.z, bv1.w);
        *(float4*)&Bs[lbk][lbn0] = bu.f;
        __syncthreads();
        #pragma unroll
        for (int kk = 0; kk < 16; ++kk) {
            const __half2* ap = (const __half2*)&As[kk][tm0];
            __half2 a01 = ap[0], a23 = ap[1], a45 = ap[2], a67 = ap[3];
            const __half2* bp = (const __half2*)&Bs[kk][tn0];
            __half2 b01 = bp[0], b23 = bp[1];
            acc[0][0] = __hfma2(__low2half2(a01),  b01, acc[0][0]);
            acc[0][1] = __hfma2(__low2half2(a01),  b23, acc[0][1]);
            acc[1][0] = __hfma2(__high2half2(a01), b01, acc[1][0]);
            acc[1][1] = __hfma2(__high2half2(a01), b23, acc[1][1]);
            acc[2][0] = __hfma2(__low2half2(a23),  b01, acc[2][0]);
            acc[2][1] = __hfma2(__low2half2(a23),  b23, acc[2][1]);
            acc[3][0] = __hfma2(__high2half2(a23), b01, acc[3][0]);
            acc[3][1] = __hfma2(__high2half2(a23), b23, acc[3][1]);
            acc[4][0] = __hfma2(__low2half2(a45),  b01, acc[4][0]);
            acc[4][1] = __hfma2(__low2half2(a45),  b23, acc[4][1]);
            acc[5][0] = __hfma2(__high2half2(a45), b01, acc[5][0]);
            acc[5][1] = __hfma2(__high2half2(a45), b23, acc[5][1]);
            acc[6][0] = __hfma2(__low2half2(a67),  b01, acc[6][0]);
            acc[6][1] = __hfma2(__low2half2(a67),  b23, acc[6][1]);
            acc[7][0] = __hfma2(__high2half2(a67), b01, acc[7][0]);
            acc[7][1] = __hfma2(__high2half2(a67), b23, acc[7][1]);
        }
        __syncthreads();
    }
    #pragma unroll
    for (int i = 0; i < 8; ++i) {
        int r = bm0 + tm0 + i;
        if (r < M) {
            __half2 dh = __float2half2_rn(dis[r]);
            H4 o;
            o.h[0] = __hmul2(acc[i][0], dh);
            o.h[1] = __hmul2(acc[i][1], dh);
            *(float2*)(C + (size_t)r * 128 + tn0) = o.f;
        }
    }
}

// ---------------- prop128 ----------------
__global__ __launch_bounds__(256) void prop128(
        const __half* __restrict__ h, const int* __restrict__ rowptr,
        const int* __restrict__ col, const float* __restrict__ dis,
        const float* __restrict__ bias, __half* __restrict__ out, int N) {
    int n = (blockIdx.x * 256 + threadIdx.x) >> 6;
    if (n >= N) return;
    int lane = threadIdx.x & 63;
    int eo = lane >> 4;
    int q = lane & 15;
    const float4* __restrict__ h4 = (const float4*)h;
    int beg = rowptr[n], end = rowptr[n + 1];
    __half2 acc[4];
    acc[0] = acc[1] = acc[2] = acc[3] = __float2half2_rn(0.f);
    int j = beg + eo;
    for (; j + 4 < end; j += 8) {
        int s0 = col[j];
        int s1 = col[j + 4];
        H8 u0, u1;
        u0.f = h4[(size_t)s0 * 16 + q];
        u1.f = h4[(size_t)s1 * 16 + q];
        acc[0] = __hadd2(acc[0], u0.h[0]);
        acc[1] = __hadd2(acc[1], u0.h[1]);
        acc[2] = __hadd2(acc[2], u0.h[2]);
        acc[3] = __hadd2(acc[3], u0.h[3]);
        acc[0] = __hadd2(acc[0], u1.h[0]);
        acc[1] = __hadd2(acc[1], u1.h[1]);
        acc[2] = __hadd2(acc[2], u1.h[2]);
        acc[3] = __hadd2(acc[3], u1.h[3]);
    }
    for (; j < end; j += 4) {
        int s = col[j];
        H8 u; u.f = h4[(size_t)s * 16 + q];
        acc[0] = __hadd2(acc[0], u.h[0]);
        acc[1] = __hadd2(acc[1], u.h[1]);
        acc[2] = __hadd2(acc[2], u.h[2]);
        acc[3] = __hadd2(acc[3], u.h[3]);
    }
    #pragma unroll
    for (int i = 0; i < 4; ++i) {
        acc[i] = __hadd2(acc[i], shfl_xor_h2(acc[i], 16));
        acc[i] = __hadd2(acc[i], shfl_xor_h2(acc[i], 32));
    }
    if (eo == 0) {
        float dn = dis[n];
        const float4* b4 = (const float4*)bias;
        float4 bA = b4[q * 2];
        float4 bB = b4[q * 2 + 1];
        float2 f0 = __half22float2(acc[0]);
        float2 f1 = __half22float2(acc[1]);
        float2 f2 = __half22float2(acc[2]);
        float2 f3 = __half22float2(acc[3]);
        float o0 = fmaf(dn, f0.x, bA.x), o1 = fmaf(dn, f0.y, bA.y);
        float o2 = fmaf(dn, f1.x, bA.z), o3 = fmaf(dn, f1.y, bA.w);
        float o4 = fmaf(dn, f2.x, bB.x), o5 = fmaf(dn, f2.y, bB.y);
        float o6 = fmaf(dn, f3.x, bB.z), o7 = fmaf(dn, f3.y, bB.w);
        o0 = o0 > 0.f ? o0 : LEAKY * o0;  o1 = o1 > 0.f ? o1 : LEAKY * o1;
        o2 = o2 > 0.f ? o2 : LEAKY * o2;  o3 = o3 > 0.f ? o3 : LEAKY * o3;
        o4 = o4 > 0.f ? o4 : LEAKY * o4;  o5 = o5 > 0.f ? o5 : LEAKY * o5;
        o6 = o6 > 0.f ? o6 : LEAKY * o6;  o7 = o7 > 0.f ? o7 : LEAKY * o7;
        H8 w;
        w.h[0] = __floats2half2_rn(o0, o1);
        w.h[1] = __floats2half2_rn(o2, o3);
        w.h[2] = __floats2half2_rn(o4, o5);
        w.h[3] = __floats2half2_rn(o6, o7);
        ((float4*)out)[(size_t)n * 16 + q] = w.f;
    }
}

// ---------------- GEMM2: fp16[M,128] @ fp32[128,16] -> fp16, *= dis[row] ----------------
__global__ __launch_bounds__(256) void gemm_128_16(
        const __half* __restrict__ A, const float* __restrict__ W,
        const float* __restrict__ dis, __half* __restrict__ C, int M) {
    __shared__ __align__(16) __half sxh[64 * 136];
    __shared__ float sw[128 * 16];
    int t = threadIdx.x;
    int n0 = blockIdx.x * 64;
    for (int i = t; i < 2048; i += 256) sw[i] = W[i];
    #pragma unroll
    for (int i = 0; i < 4; ++i) {
        int l = t + i * 256;
        int node = l >> 4, q = l & 15;
        int gn = n0 + node;
        float4 v = make_float4(0.f, 0.f, 0.f, 0.f);
        if (gn < M) v = ((const float4*)A)[(size_t)gn * 16 + q];
        *(float4*)&sxh[node * 136 + q * 8] = v;
    }
    __syncthreads();
    int n = t >> 2;
    int c0 = (t & 3) * 4;
    const float4* sw4 = (const float4*)sw;
    float4 acc = make_float4(0.f, 0.f, 0.f, 0.f);
    for (int k = 0; k < 128; k += 2) {
        __half2 xv2 = *(const __half2*)&sxh[n * 136 + k];
        float2 xf = __half22float2(xv2);
        float4 w0 = sw4[k * 4 + (t & 3)];
        float4 w1 = sw4[(k + 1) * 4 + (t & 3)];
        acc.x += xf.x * w0.x + xf.y * w1.x;
        acc.y += xf.x * w0.y + xf.y * w1.y;
        acc.z += xf.x * w0.z + xf.y * w1.z;
        acc.w += xf.x * w0.w + xf.y * w1.w;
    }
    int gn = n0 + n;
    if (gn < M) {
        float w = dis[gn];
        H4 o;
        o.h[0] = __floats2half2_rn(acc.x * w, acc.y * w);
        o.h[1] = __floats2half2_rn(acc.z * w, acc.w * w);
        *(float2*)(C + (size_t)gn * 16 + c0) = o.f;
    }
}

// ---------------- prop16 ----------------
__global__ __launch_bounds__(256) void prop16(
        const __half* __restrict__ h, const int* __restrict__ rowptr,
        const int* __restrict__ col, const float* __restrict__ dis,
        const float* __restrict__ bias, void* __restrict__ outp,
        int N, int act, int post, int out_fp16) {
    int t = blockIdx.x * 256 + threadIdx.x;
    int n = t >> 4;
    if (n >= N) return;
    int li = threadIdx.x & 15;
    int eo = li >> 3;
    int hq = li & 7;
    const int* __restrict__ h2i = (const int*)h;
    int beg = rowptr[n], end = rowptr[n + 1];
    __half2 acc = __float2half2_rn(0.f);
    int j = beg + eo;
    for (; j + 6 < end; j += 8) {
        H2 u0, u1, u2, u3;
        u0.i = h2i[(size_t)col[j]     * 8 + hq];
        u1.i = h2i[(size_t)col[j + 2] * 8 + hq];
        u2.i = h2i[(size_t)col[j + 4] * 8 + hq];
        u3.i = h2i[(size_t)col[j + 6] * 8 + hq];
        acc = __hadd2(acc, u0.h);
        acc = __hadd2(acc, u1.h);
        acc = __hadd2(acc, u2.h);
        acc = __hadd2(acc, u3.h);
    }
    for (; j < end; j += 2) {
        H2 u; u.i = h2i[(size_t)col[j] * 8 + hq];
        acc = __hadd2(acc, u.h);
    }
    acc = __hadd2(acc, shfl_xor_h2(acc, 8));
    if (eo == 0) {
        float dn = dis[n];
        float2 f = __half22float2(acc);
        float ox = dn * f.x, oy = dn * f.y;
        if (act) {
            ox += bias[hq * 2];
            oy += bias[hq * 2 + 1];
            ox = ox > 0.f ? ox : LEAKY * ox;
            oy = oy > 0.f ? oy : LEAKY * oy;
        }
        if (post) { ox *= dn; oy *= dn; }
        if (out_fp16) {
            H2 w; w.h = __floats2half2_rn(ox, oy);
            ((int*)outp)[(size_t)n * 8 + hq] = w.i;
        } else {
            ((float2*)outp)[(size_t)n * 8 + hq] = make_float2(ox, oy);
        }
    }
}

// ---------------- GEMM3: [M,16] @ [16,40] + b ----------------
__global__ __launch_bounds__(256) void gemm_16_40(
        const float* __restrict__ P, const float* __restrict__ W,
        const float* __restrict__ b, float* __restrict__ out, int total) {
    __shared__ float sw[16 * 40];
    __shared__ float sb[40];
    int t = threadIdx.x;
    for (int i = t; i < 640; i += 256) sw[i] = W[i];
    if (t < 40) sb[t] = b[t];
    __syncthreads();
    int idx = blockIdx.x * 256 + t;
    if (idx >= total) return;
    int n = idx / 40, c = idx % 40;
    float acc = sb[c];
    const float* pr = P + (size_t)n * 16;
    #pragma unroll
    for (int k = 0; k < 16; ++k) acc += pr[k] * sw[k * 40 + c];
    out[idx] = acc;
}

// ---------------- launch ----------------

extern "C" void kernel_launch(void* const* d_in, const int* in_sizes, int n_in,
                              void* d_out, int out_size, void* d_ws, size_t ws_size,
                              hipStream_t stream) {
    const float* x  = (const float*)d_in[0];
    const int*   ei = (const int*)d_in[1];
    const float* W1 = (const float*)d_in[2];
    const float* b1 = (const float*)d_in[3];
    const float* W2 = (const float*)d_in[4];
    const float* b2 = (const float*)d_in[5];
    const float* W3 = (const float*)d_in[6];
    const float* b3 = (const float*)d_in[7];
    float* out = (float*)d_out;

    int N = in_sizes[0] / 256;   // 100000
    int E = in_sizes[1] / 2;     // 3200000
    const int* src = ei;
    const int* dst = ei + E;
    int NBUK = (N + BSZ - 1) >> BP;   // 3125

    char* w = (char*)d_ws;
    auto alloc = [&](size_t bytes) {
        char* p = w;
        w += (bytes + 255) & ~(size_t)255;
        return p;
    };
    int NB = (N + 255) / 256;
    int*    cnt     = (int*)   alloc((size_t)N * 4);
    int*    rowptr  = (int*)   alloc((size_t)(N + 1) * 4);
    int*    bsum    = (int*)   alloc((size_t)NB * 4);
    int*    bhist   = (int*)   alloc((size_t)NBUK * 4);
    int*    bbase   = (int*)   alloc((size_t)(NBUK + 1) * 4);
    int*    bcur    = (int*)   alloc((size_t)NBUK * 4);
    int*    ebuf    = (int*)   alloc((size_t)E * 4);
    int*    colx    = (int*)   alloc((size_t)(E + N) * 4);
    float*  dis     = (float*) alloc((size_t)N * 4);
    __half* h1h     = (__half*)alloc((size_t)N * 128 * 2);
    __half* x1h     = (__half*)alloc((size_t)N * 128 * 2);
    __half* h2h     = (__half*)alloc((size_t)N * 16 * 2);
    __half* x2h     = (__half*)alloc((size_t)N * 16 * 2);
    float*  p3      = (float*) alloc((size_t)N * 16 * 4);

    hipMemsetAsync(bhist, 0, (size_t)NBUK * 4, stream);
    khist   <<<256, 256, (size_t)NBUK * 4, stream>>>(dst, bhist, E, NBUK);
    bscan   <<<1, 1024, 0, stream>>>(bhist, bbase, bcur, NBUK);
    kscatter<<<(E + 255) / 256, 256, 0, stream>>>(src, dst, bcur, ebuf, E);
    kcount  <<<NBUK, 256, 0, stream>>>(ebuf, bbase, cnt, dis, N);
    scan_block<<<NB, 256, 0, stream>>>(cnt, rowptr, bsum, N);
    scan_tops <<<1, 512, 0, stream>>>(bsum, NB, rowptr, N);
    scan_add  <<<NB, 256, 0, stream>>>(rowptr, bsum, N);
    kplace  <<<NBUK, 256, 0, stream>>>(ebuf, bbase, rowptr, colx, N);

    gemm_256_128<<<(N + 63) / 64, 256, 0, stream>>>(x, W1, dis, h1h, N);
    prop128     <<<(N * 64 + 255) / 256, 256, 0, stream>>>(h1h, rowptr, colx,
                                                           dis, b1, x1h, N);
    gemm_128_16 <<<(N + 63) / 64, 256, 0, stream>>>(x1h, W2, dis, h2h, N);
    prop16      <<<(N * 16 + 255) / 256, 256, 0, stream>>>(h2h, rowptr, colx,
                                                           dis, b2, x2h, N, 1, 1, 1);
    prop16      <<<(N * 16 + 255) / 256, 256, 0, stream>>>(x2h, rowptr, colx,
                                                           dis, nullptr, p3, N, 0, 0, 0);
    gemm_16_40  <<<(N * 40 + 255) / 256, 256, 0, stream>>>(p3, W3, b3, out,
                                                           N * 40);
}

// Round 5
// 560.270 us; speedup vs baseline: 1.3175x; 1.3175x over previous
//
#include <hip/hip_runtime.h>
#include <hip/hip_fp16.h>
#include <math.h>

#define LEAKY 0.2f
#define BP 6                     // nodes per bucket = 64
#define BSZ 64
#define NBUK_MAX 2048

union H2 { __half2 h; int i; };
union H4 { __half2 h[2]; float2 f; };
union H8 { __half2 h[4]; float4 f; };

__device__ inline __half2 shfl_xor_h2(__half2 v, int m) {
    H2 u; u.h = v;
    u.i = __shfl_xor(u.i, m);
    return u.h;
}

// ---------------- CSR build (block-local binning) ----------------

// global bucket totals via per-block LDS histogram
__global__ __launch_bounds__(256) void khist(const int* __restrict__ dst,
                                             int* __restrict__ bhist,
                                             int E, int nbuk) {
    __shared__ int hist[NBUK_MAX];
    int t = threadIdx.x;
    for (int i = t; i < nbuk; i += 256) hist[i] = 0;
    __syncthreads();
    for (int e = blockIdx.x * 256 + t; e < E; e += gridDim.x * 256)
        atomicAdd(&hist[dst[e] >> BP], 1);
    __syncthreads();
    for (int i = t; i < nbuk; i += 256) {
        int v = hist[i];
        if (v) atomicAdd(&bhist[i], v);
    }
}

// single-block exclusive scan of bucket counts -> bbase, bcur
__global__ __launch_bounds__(1024) void bscan(const int* __restrict__ bhist,
                                              int* __restrict__ bbase,
                                              int* __restrict__ bcur, int nbuk) {
    __shared__ int s[1024];
    int t = threadIdx.x;
    int v[4]; int sum = 0;
    #pragma unroll
    for (int i = 0; i < 4; ++i) {
        int idx = t * 4 + i;
        v[i] = (idx < nbuk) ? bhist[idx] : 0;
        sum += v[i];
    }
    s[t] = sum; __syncthreads();
    for (int off = 1; off < 1024; off <<= 1) {
        int a = (t >= off) ? s[t - off] : 0;
        __syncthreads();
        s[t] += a;
        __syncthreads();
    }
    int run = (t > 0) ? s[t - 1] : 0;
    #pragma unroll
    for (int i = 0; i < 4; ++i) {
        int idx = t * 4 + i;
        if (idx < nbuk) { bbase[idx] = run; bcur[idx] = run; run += v[i]; }
    }
    if (t == 1023) bbase[nbuk] = s[1023];
}

// block-local binning scatter: LDS hist -> per-(block,bucket) segment
// reservation -> segment-contiguous writes of packed (dlocal<<17)|src
__global__ __launch_bounds__(256) void kscatter2(const int* __restrict__ src,
                                                 const int* __restrict__ dst,
                                                 int* __restrict__ bcur,
                                                 int* __restrict__ ebuf,
                                                 int E, int nbuk, int chunk) {
    __shared__ int hist[NBUK_MAX];
    int t = threadIdx.x;
    int base = blockIdx.x * chunk;
    int end = min(base + chunk, E);
    for (int i = t; i < nbuk; i += 256) hist[i] = 0;
    __syncthreads();
    // phase A: local histogram
    for (int e = base + t; e < end; e += 256)
        atomicAdd(&hist[dst[e] >> BP], 1);
    __syncthreads();
    // phase B: reserve global segments, hist[i] becomes write cursor
    for (int i = t; i < nbuk; i += 256) {
        int c = hist[i];
        hist[i] = c ? atomicAdd(&bcur[i], c) : 0;
    }
    __syncthreads();
    // phase C: scatter into own segments
    for (int e = base + t; e < end; e += 256) {
        int d = dst[e];
        int pos = atomicAdd(&hist[d >> BP], 1);
        ebuf[pos] = ((d & (BSZ - 1)) << 17) | src[e];
    }
}

// per-bucket node counts (+self-loop) and dis
__global__ __launch_bounds__(256) void kcount(const int* __restrict__ ebuf,
                                              const int* __restrict__ bbase,
                                              int* __restrict__ cnt,
                                              float* __restrict__ dis, int N) {
    __shared__ int h[BSZ];
    int b = blockIdx.x, t = threadIdx.x;
    if (t < BSZ) h[t] = 0;
    __syncthreads();
    int beg = bbase[b], end = bbase[b + 1];
    for (int j = beg + t; j < end; j += 256)
        atomicAdd(&h[(ebuf[j] >> 17) & (BSZ - 1)], 1);
    __syncthreads();
    if (t < BSZ) {
        int node = b * BSZ + t;
        if (node < N) {
            int c = h[t] + 1;
            cnt[node] = c;
            dis[node] = rsqrtf((float)c);
        }
    }
}

__global__ void scan_block(const int* __restrict__ cnt, int* rowptr, int* bsum, int n) {
    __shared__ int s[256];
    int t = threadIdx.x;
    int i = blockIdx.x * 256 + t;
    int v = (i < n) ? cnt[i] : 0;
    s[t] = v; __syncthreads();
    for (int off = 1; off < 256; off <<= 1) {
        int a = (t >= off) ? s[t - off] : 0;
        __syncthreads();
        s[t] += a;
        __syncthreads();
    }
    if (i < n) rowptr[i] = s[t] - v;
    if (t == 255) bsum[blockIdx.x] = s[255];
}

__global__ void scan_tops(int* bsum, int nb, int* rowptr, int n) {
    __shared__ int s[512];
    int t = threadIdx.x;
    int v = (t < nb) ? bsum[t] : 0;
    s[t] = v; __syncthreads();
    for (int off = 1; off < 512; off <<= 1) {
        int a = (t >= off) ? s[t - off] : 0;
        __syncthreads();
        s[t] += a;
        __syncthreads();
    }
    if (t < nb) bsum[t] = s[t] - v;
    if (t == 511) rowptr[n] = s[511];
}

__global__ void scan_add(int* rowptr, const int* __restrict__ bsum, int n) {
    int i = blockIdx.x * 256 + threadIdx.x;
    if (i < n) rowptr[i] += bsum[blockIdx.x];
}

// per-bucket placement into col (self-loop first, then bucket edges)
__global__ __launch_bounds__(256) void kplace(const int* __restrict__ ebuf,
                                              const int* __restrict__ bbase,
                                              const int* __restrict__ rowptr,
                                              int* __restrict__ col, int N) {
    __shared__ int cur[BSZ];
    int b = blockIdx.x, t = threadIdx.x;
    if (t < BSZ) {
        int node = b * BSZ + t;
        if (node < N) {
            int r = rowptr[node];
            col[r] = node;          // self-loop
            cur[t] = r + 1;
        }
    }
    __syncthreads();
    int beg = bbase[b], end = bbase[b + 1];
    for (int j = beg + t; j < end; j += 256) {
        int v = ebuf[j];
        int dl = (v >> 17) & (BSZ - 1);
        int p = atomicAdd(&cur[dl], 1);
        col[p] = v & 0x1FFFF;
    }
}

// ---------------- GEMM1: [M,256] @ [256,128] -> fp16, epilogue *= dis[row] ----------------
__global__ __launch_bounds__(256) void gemm_256_128(
        const float* __restrict__ A, const float* __restrict__ B,
        const float* __restrict__ dis, __half* __restrict__ C, int M) {
    __shared__ __align__(16) __half As[16][72];
    __shared__ __align__(16) __half Bs[16][136];
    int t = threadIdx.x;
    int bm0 = blockIdx.x * 64;
    int lm  = t >> 2;
    int lk0 = (t & 3) * 4;
    int lbk  = t >> 4;
    int lbn0 = (t & 15) * 8;
    int arow = bm0 + lm;
    bool aval = arow < M;
    const float* Arow = A + (size_t)arow * 256;
    int tm0 = (t >> 5) * 8;
    int tn0 = (t & 31) * 4;
    __half2 acc[8][2];
    #pragma unroll
    for (int i = 0; i < 8; ++i) {
        acc[i][0] = __float2half2_rn(0.f);
        acc[i][1] = __float2half2_rn(0.f);
    }
    for (int kb = 0; kb < 256; kb += 16) {
        float4 av = make_float4(0.f, 0.f, 0.f, 0.f);
        if (aval) av = *(const float4*)(Arow + kb + lk0);
        float4 bv0 = *(const float4*)(B + (size_t)(kb + lbk) * 128 + lbn0);
        float4 bv1 = *(const float4*)(B + (size_t)(kb + lbk) * 128 + lbn0 + 4);
        As[lk0 + 0][lm] = __float2half(av.x);
        As[lk0 + 1][lm] = __float2half(av.y);
        As[lk0 + 2][lm] = __float2half(av.z);
        As[lk0 + 3][lm] = __float2half(av.w);
        H8 bu;
        bu.h[0] = __floats2half2_rn(bv0.x, bv0.y);
        bu.h[1] = __floats2half2_rn(bv0.z, bv0.w);
        bu.h[2] = __floats2half2_rn(bv1.x, bv1.y);
        bu.h[3] = __floats2half2_rn(bv1.z, bv1.w);
        *(float4*)&Bs[lbk][lbn0] = bu.f;
        __syncthreads();
        #pragma unroll
        for (int kk = 0; kk < 16; ++kk) {
            const __half2* ap = (const __half2*)&As[kk][tm0];
            __half2 a01 = ap[0], a23 = ap[1], a45 = ap[2], a67 = ap[3];
            const __half2* bp = (const __half2*)&Bs[kk][tn0];
            __half2 b01 = bp[0], b23 = bp[1];
            acc[0][0] = __hfma2(__low2half2(a01),  b01, acc[0][0]);
            acc[0][1] = __hfma2(__low2half2(a01),  b23, acc[0][1]);
            acc[1][0] = __hfma2(__high2half2(a01), b01, acc[1][0]);
            acc[1][1] = __hfma2(__high2half2(a01), b23, acc[1][1]);
            acc[2][0] = __hfma2(__low2half2(a23),  b01, acc[2][0]);
            acc[2][1] = __hfma2(__low2half2(a23),  b23, acc[2][1]);
            acc[3][0] = __hfma2(__high2half2(a23), b01, acc[3][0]);
            acc[3][1] = __hfma2(__high2half2(a23), b23, acc[3][1]);
            acc[4][0] = __hfma2(__low2half2(a45),  b01, acc[4][0]);
            acc[4][1] = __hfma2(__low2half2(a45),  b23, acc[4][1]);
            acc[5][0] = __hfma2(__high2half2(a45), b01, acc[5][0]);
            acc[5][1] = __hfma2(__high2half2(a45), b23, acc[5][1]);
            acc[6][0] = __hfma2(__low2half2(a67),  b01, acc[6][0]);
            acc[6][1] = __hfma2(__low2half2(a67),  b23, acc[6][1]);
            acc[7][0] = __hfma2(__high2half2(a67), b01, acc[7][0]);
            acc[7][1] = __hfma2(__high2half2(a67), b23, acc[7][1]);
        }
        __syncthreads();
    }
    #pragma unroll
    for (int i = 0; i < 8; ++i) {
        int r = bm0 + tm0 + i;
        if (r < M) {
            __half2 dh = __float2half2_rn(dis[r]);
            H4 o;
            o.h[0] = __hmul2(acc[i][0], dh);
            o.h[1] = __hmul2(acc[i][1], dh);
            *(float2*)(C + (size_t)r * 128 + tn0) = o.f;
        }
    }
}

// ---------------- prop128 ----------------
__global__ __launch_bounds__(256) void prop128(
        const __half* __restrict__ h, const int* __restrict__ rowptr,
        const int* __restrict__ col, const float* __restrict__ dis,
        const float* __restrict__ bias, __half* __restrict__ out, int N) {
    int n = (blockIdx.x * 256 + threadIdx.x) >> 6;
    if (n >= N) return;
    int lane = threadIdx.x & 63;
    int eo = lane >> 4;
    int q = lane & 15;
    const float4* __restrict__ h4 = (const float4*)h;
    int beg = rowptr[n], end = rowptr[n + 1];
    __half2 acc[4];
    acc[0] = acc[1] = acc[2] = acc[3] = __float2half2_rn(0.f);
    int j = beg + eo;
    for (; j + 4 < end; j += 8) {
        int s0 = col[j];
        int s1 = col[j + 4];
        H8 u0, u1;
        u0.f = h4[(size_t)s0 * 16 + q];
        u1.f = h4[(size_t)s1 * 16 + q];
        acc[0] = __hadd2(acc[0], u0.h[0]);
        acc[1] = __hadd2(acc[1], u0.h[1]);
        acc[2] = __hadd2(acc[2], u0.h[2]);
        acc[3] = __hadd2(acc[3], u0.h[3]);
        acc[0] = __hadd2(acc[0], u1.h[0]);
        acc[1] = __hadd2(acc[1], u1.h[1]);
        acc[2] = __hadd2(acc[2], u1.h[2]);
        acc[3] = __hadd2(acc[3], u1.h[3]);
    }
    for (; j < end; j += 4) {
        int s = col[j];
        H8 u; u.f = h4[(size_t)s * 16 + q];
        acc[0] = __hadd2(acc[0], u.h[0]);
        acc[1] = __hadd2(acc[1], u.h[1]);
        acc[2] = __hadd2(acc[2], u.h[2]);
        acc[3] = __hadd2(acc[3], u.h[3]);
    }
    #pragma unroll
    for (int i = 0; i < 4; ++i) {
        acc[i] = __hadd2(acc[i], shfl_xor_h2(acc[i], 16));
        acc[i] = __hadd2(acc[i], shfl_xor_h2(acc[i], 32));
    }
    if (eo == 0) {
        float dn = dis[n];
        const float4* b4 = (const float4*)bias;
        float4 bA = b4[q * 2];
        float4 bB = b4[q * 2 + 1];
        float2 f0 = __half22float2(acc[0]);
        float2 f1 = __half22float2(acc[1]);
        float2 f2 = __half22float2(acc[2]);
        float2 f3 = __half22float2(acc[3]);
        float o0 = fmaf(dn, f0.x, bA.x), o1 = fmaf(dn, f0.y, bA.y);
        float o2 = fmaf(dn, f1.x, bA.z), o3 = fmaf(dn, f1.y, bA.w);
        float o4 = fmaf(dn, f2.x, bB.x), o5 = fmaf(dn, f2.y, bB.y);
        float o6 = fmaf(dn, f3.x, bB.z), o7 = fmaf(dn, f3.y, bB.w);
        o0 = o0 > 0.f ? o0 : LEAKY * o0;  o1 = o1 > 0.f ? o1 : LEAKY * o1;
        o2 = o2 > 0.f ? o2 : LEAKY * o2;  o3 = o3 > 0.f ? o3 : LEAKY * o3;
        o4 = o4 > 0.f ? o4 : LEAKY * o4;  o5 = o5 > 0.f ? o5 : LEAKY * o5;
        o6 = o6 > 0.f ? o6 : LEAKY * o6;  o7 = o7 > 0.f ? o7 : LEAKY * o7;
        H8 w;
        w.h[0] = __floats2half2_rn(o0, o1);
        w.h[1] = __floats2half2_rn(o2, o3);
        w.h[2] = __floats2half2_rn(o4, o5);
        w.h[3] = __floats2half2_rn(o6, o7);
        ((float4*)out)[(size_t)n * 16 + q] = w.f;
    }
}

// ---------------- GEMM2: fp16[M,128] @ fp32[128,16] -> fp16, *= dis[row] ----------------
__global__ __launch_bounds__(256) void gemm_128_16(
        const __half* __restrict__ A, const float* __restrict__ W,
        const float* __restrict__ dis, __half* __restrict__ C, int M) {
    __shared__ __align__(16) __half sxh[64 * 136];
    __shared__ float sw[128 * 16];
    int t = threadIdx.x;
    int n0 = blockIdx.x * 64;
    for (int i = t; i < 2048; i += 256) sw[i] = W[i];
    #pragma unroll
    for (int i = 0; i < 4; ++i) {
        int l = t + i * 256;
        int node = l >> 4, q = l & 15;
        int gn = n0 + node;
        float4 v = make_float4(0.f, 0.f, 0.f, 0.f);
        if (gn < M) v = ((const float4*)A)[(size_t)gn * 16 + q];
        *(float4*)&sxh[node * 136 + q * 8] = v;
    }
    __syncthreads();
    int n = t >> 2;
    int c0 = (t & 3) * 4;
    const float4* sw4 = (const float4*)sw;
    float4 acc = make_float4(0.f, 0.f, 0.f, 0.f);
    for (int k = 0; k < 128; k += 2) {
        __half2 xv2 = *(const __half2*)&sxh[n * 136 + k];
        float2 xf = __half22float2(xv2);
        float4 w0 = sw4[k * 4 + (t & 3)];
        float4 w1 = sw4[(k + 1) * 4 + (t & 3)];
        acc.x += xf.x * w0.x + xf.y * w1.x;
        acc.y += xf.x * w0.y + xf.y * w1.y;
        acc.z += xf.x * w0.z + xf.y * w1.z;
        acc.w += xf.x * w0.w + xf.y * w1.w;
    }
    int gn = n0 + n;
    if (gn < M) {
        float w = dis[gn];
        H4 o;
        o.h[0] = __floats2half2_rn(acc.x * w, acc.y * w);
        o.h[1] = __floats2half2_rn(acc.z * w, acc.w * w);
        *(float2*)(C + (size_t)gn * 16 + c0) = o.f;
    }
}

// ---------------- prop16 ----------------
__global__ __launch_bounds__(256) void prop16(
        const __half* __restrict__ h, const int* __restrict__ rowptr,
        const int* __restrict__ col, const float* __restrict__ dis,
        const float* __restrict__ bias, void* __restrict__ outp,
        int N, int act, int post, int out_fp16) {
    int t = blockIdx.x * 256 + threadIdx.x;
    int n = t >> 4;
    if (n >= N) return;
    int li = threadIdx.x & 15;
    int eo = li >> 3;
    int hq = li & 7;
    const int* __restrict__ h2i = (const int*)h;
    int beg = rowptr[n], end = rowptr[n + 1];
    __half2 acc = __float2half2_rn(0.f);
    int j = beg + eo;
    for (; j + 6 < end; j += 8) {
        H2 u0, u1, u2, u3;
        u0.i = h2i[(size_t)col[j]     * 8 + hq];
        u1.i = h2i[(size_t)col[j + 2] * 8 + hq];
        u2.i = h2i[(size_t)col[j + 4] * 8 + hq];
        u3.i = h2i[(size_t)col[j + 6] * 8 + hq];
        acc = __hadd2(acc, u0.h);
        acc = __hadd2(acc, u1.h);
        acc = __hadd2(acc, u2.h);
        acc = __hadd2(acc, u3.h);
    }
    for (; j < end; j += 2) {
        H2 u; u.i = h2i[(size_t)col[j] * 8 + hq];
        acc = __hadd2(acc, u.h);
    }
    acc = __hadd2(acc, shfl_xor_h2(acc, 8));
    if (eo == 0) {
        float dn = dis[n];
        float2 f = __half22float2(acc);
        float ox = dn * f.x, oy = dn * f.y;
        if (act) {
            ox += bias[hq * 2];
            oy += bias[hq * 2 + 1];
            ox = ox > 0.f ? ox : LEAKY * ox;
            oy = oy > 0.f ? oy : LEAKY * oy;
        }
        if (post) { ox *= dn; oy *= dn; }
        if (out_fp16) {
            H2 w; w.h = __floats2half2_rn(ox, oy);
            ((int*)outp)[(size_t)n * 8 + hq] = w.i;
        } else {
            ((float2*)outp)[(size_t)n * 8 + hq] = make_float2(ox, oy);
        }
    }
}

// ---------------- GEMM3: [M,16] @ [16,40] + b ----------------
__global__ __launch_bounds__(256) void gemm_16_40(
        const float* __restrict__ P, const float* __restrict__ W,
        const float* __restrict__ b, float* __restrict__ out, int total) {
    __shared__ float sw[16 * 40];
    __shared__ float sb[40];
    int t = threadIdx.x;
    for (int i = t; i < 640; i += 256) sw[i] = W[i];
    if (t < 40) sb[t] = b[t];
    __syncthreads();
    int idx = blockIdx.x * 256 + t;
    if (idx >= total) return;
    int n = idx / 40, c = idx % 40;
    float acc = sb[c];
    const float* pr = P + (size_t)n * 16;
    #pragma unroll
    for (int k = 0; k < 16; ++k) acc += pr[k] * sw[k * 40 + c];
    out[idx] = acc;
}

// ---------------- launch ----------------

extern "C" void kernel_launch(void* const* d_in, const int* in_sizes, int n_in,
                              void* d_out, int out_size, void* d_ws, size_t ws_size,
                              hipStream_t stream) {
    const float* x  = (const float*)d_in[0];
    const int*   ei = (const int*)d_in[1];
    const float* W1 = (const float*)d_in[2];
    const float* b1 = (const float*)d_in[3];
    const float* W2 = (const float*)d_in[4];
    const float* b2 = (const float*)d_in[5];
    const float* W3 = (const float*)d_in[6];
    const float* b3 = (const float*)d_in[7];
    float* out = (float*)d_out;

    int N = in_sizes[0] / 256;   // 100000
    int E = in_sizes[1] / 2;     // 3200000
    const int* src = ei;
    const int* dst = ei + E;
    int NBUK = (N + BSZ - 1) >> BP;   // 1563

    char* w = (char*)d_ws;
    auto alloc = [&](size_t bytes) {
        char* p = w;
        w += (bytes + 255) & ~(size_t)255;
        return p;
    };
    int NB = (N + 255) / 256;
    int*    cnt     = (int*)   alloc((size_t)N * 4);
    int*    rowptr  = (int*)   alloc((size_t)(N + 1) * 4);
    int*    bsum    = (int*)   alloc((size_t)NB * 4);
    int*    bhist   = (int*)   alloc((size_t)NBUK * 4);
    int*    bbase   = (int*)   alloc((size_t)(NBUK + 1) * 4);
    int*    bcur    = (int*)   alloc((size_t)NBUK * 4);
    int*    ebuf    = (int*)   alloc((size_t)E * 4);
    int*    colx    = (int*)   alloc((size_t)(E + N) * 4);
    float*  dis     = (float*) alloc((size_t)N * 4);
    __half* h1h     = (__half*)alloc((size_t)N * 128 * 2);
    __half* x1h     = (__half*)alloc((size_t)N * 128 * 2);
    __half* h2h     = (__half*)alloc((size_t)N * 16 * 2);
    __half* x2h     = (__half*)alloc((size_t)N * 16 * 2);
    float*  p3      = (float*) alloc((size_t)N * 16 * 4);

    hipMemsetAsync(bhist, 0, (size_t)NBUK * 4, stream);
    khist   <<<256, 256, 0, stream>>>(dst, bhist, E, NBUK);
    bscan   <<<1, 1024, 0, stream>>>(bhist, bbase, bcur, NBUK);
    int SC_BLOCKS = 256;
    int chunk = (E + SC_BLOCKS - 1) / SC_BLOCKS;
    kscatter2<<<SC_BLOCKS, 256, 0, stream>>>(src, dst, bcur, ebuf, E, NBUK, chunk);
    kcount  <<<NBUK, 256, 0, stream>>>(ebuf, bbase, cnt, dis, N);
    scan_block<<<NB, 256, 0, stream>>>(cnt, rowptr, bsum, N);
    scan_tops <<<1, 512, 0, stream>>>(bsum, NB, rowptr, N);
    scan_add  <<<NB, 256, 0, stream>>>(rowptr, bsum, N);
    kplace  <<<NBUK, 256, 0, stream>>>(ebuf, bbase, rowptr, colx, N);

    gemm_256_128<<<(N + 63) / 64, 256, 0, stream>>>(x, W1, dis, h1h, N);
    prop128     <<<(N * 64 + 255) / 256, 256, 0, stream>>>(h1h, rowptr, colx,
                                                           dis, b1, x1h, N);
    gemm_128_16 <<<(N + 63) / 64, 256, 0, stream>>>(x1h, W2, dis, h2h, N);
    prop16      <<<(N * 16 + 255) / 256, 256, 0, stream>>>(h2h, rowptr, colx,
                                                           dis, b2, x2h, N, 1, 1, 1);
    prop16      <<<(N * 16 + 255) / 256, 256, 0, stream>>>(x2h, rowptr, colx,
                                                           dis, nullptr, p3, N, 0, 0, 0);
    gemm_16_40  <<<(N * 40 + 255) / 256, 256, 0, stream>>>(p3, W3, b3, out,
                                                           N * 40);
}